// Round 3
// baseline (134.399 us; speedup 1.0000x reference)
//
#include <hip/hip_runtime.h>

// StericClashConstraint: N=16384 pts [N,3] fp32.
// out[0..3N-1] = pos passthrough; out[3N] = mean(max(1-dist,0), diag=0) * 0.02
//
// Round 3: symmetric (strict upper triangle x2, 1.78x less pair work),
// per-k ballot gating (p=4.7% per 64-pair vote vs 32% per 512 in R2),
// raw v_sqrt_f32 via __builtin_amdgcn_sqrtf (1 instr vs ~10 libm fixup seq).
// Diagonal excluded exactly by j>i mask inside the gated path of diag blocks.

constexpr int BLOCK = 256;
constexpr int IPT   = 8;            // i's per thread
constexpr int IC    = BLOCK * IPT;  // 2048 i's per block
constexpr int TJ    = 32;           // j's per block (staged once, no loop barriers)
constexpr int N     = 16384;
constexpr int NT    = N / TJ;       // 512 j-tiles total
constexpr int TPC   = IC / TJ;      // 64 j-tiles spanned by one i-chunk
constexpr int NX    = N / IC;       // 8 i-chunks
constexpr int NDIAG = NX * TPC;     // 512 diagonal blocks
constexpr int NFULL = 1792;         // sum_x (NT - TPC*(x+1))
constexpr int NB    = NDIAG + NFULL;// 2304 blocks, ~9/CU

__global__ void __launch_bounds__(BLOCK, 4)
pair_kernel(const float* __restrict__ pos, float* __restrict__ out,
            float* __restrict__ acc, unsigned int* __restrict__ cnt) {
    __shared__ float4 tile[TJ];
    __shared__ float  wsum[BLOCK / 64];

    const int b = blockIdx.x;
    const int t = threadIdx.x;

    // ---- decode block -> (x i-chunk, jt j-tile, diag?) ; all scalar/uniform
    int x, jt;
    bool diag;
    if (b < NDIAG) {
        x = b >> 6;                  // b / TPC
        jt = (x << 6) + (b & 63);    // j-range inside i-range
        diag = true;
    } else {
        int b2 = b - NDIAG;
        x = 0;
        for (int xx = 0; xx < NX; ++xx) {         // uniform 8-iter decode
            const int c = NT - TPC * (xx + 1);
            if (b2 < c) { x = xx; break; }
            b2 -= c;
        }
        jt = TPC * (x + 1) + b2;
        diag = false;
    }

    // ---- pos -> out passthrough, spread over the 512 diag blocks (24 float4 each)
    if (b < NDIAG && t < 24) {
        reinterpret_cast<float4*>(out)[b * 24 + t] =
            reinterpret_cast<const float4*>(pos)[b * 24 + t];
    }

    // ---- stage j-tile {x,y,z,|p|^2}, once per block
    const int j0 = jt * TJ;
    if (t < TJ) {
        const float* p = pos + (size_t)(j0 + t) * 3;
        const float px = p[0], py = p[1], pz = p[2];
        tile[t] = make_float4(px, py, pz, fmaf(px, px, fmaf(py, py, pz * pz)));
    }

    // ---- i fragments (gram form): tt = sqj - 2*dot ;  violation iff tt < thr = 1 - sqi
    const int ibt = x * IC + t;
    float xi2[IPT], yi2[IPT], zi2[IPT], thr[IPT], sqi[IPT];
    #pragma unroll
    for (int k = 0; k < IPT; ++k) {
        const float* p = pos + (size_t)(ibt + (k << 8)) * 3;
        const float px = p[0], py = p[1], pz = p[2];
        xi2[k] = -2.0f * px;
        yi2[k] = -2.0f * py;
        zi2[k] = -2.0f * pz;
        sqi[k] = fmaf(px, px, fmaf(py, py, pz * pz));
        thr[k] = 1.0f - sqi[k];
    }

    __syncthreads();

    float s = 0.0f;
    if (!diag) {
        // full blocks: every (i,j) here has j > i — no mask
        #pragma unroll 4
        for (int q = 0; q < TJ; ++q) {
            const float4 pj = tile[q];
            float tt[IPT];
            #pragma unroll
            for (int k = 0; k < IPT; ++k) {
                float d = fmaf(xi2[k], pj.x, pj.w);
                d = fmaf(yi2[k], pj.y, d);
                tt[k] = fmaf(zi2[k], pj.z, d);
            }
            #pragma unroll
            for (int k = 0; k < IPT; ++k) {
                if (__ballot(tt[k] < thr[k])) {          // 64-pair vote, ~4.7% taken
                    if (tt[k] < thr[k]) {
                        const float d2 = fmaxf(tt[k] + sqi[k], 0.0f);
                        s += 1.0f - __builtin_amdgcn_sqrtf(d2);
                    }
                }
            }
        }
    } else {
        // diagonal blocks: keep only j > i (excludes i==j exactly)
        #pragma unroll 4
        for (int q = 0; q < TJ; ++q) {
            const float4 pj = tile[q];
            const int jj = j0 + q;
            float tt[IPT];
            #pragma unroll
            for (int k = 0; k < IPT; ++k) {
                float d = fmaf(xi2[k], pj.x, pj.w);
                d = fmaf(yi2[k], pj.y, d);
                tt[k] = fmaf(zi2[k], pj.z, d);
            }
            #pragma unroll
            for (int k = 0; k < IPT; ++k) {
                if (__ballot(tt[k] < thr[k])) {
                    if ((tt[k] < thr[k]) && (jj > ibt + (k << 8))) {
                        const float d2 = fmaxf(tt[k] + sqi[k], 0.0f);
                        s += 1.0f - __builtin_amdgcn_sqrtf(d2);
                    }
                }
            }
        }
    }

    // ---- reduce: wave shuffle -> LDS -> one atomic per block
    for (int off = 32; off > 0; off >>= 1) s += __shfl_down(s, off);
    if ((t & 63) == 0) wsum[t >> 6] = s;
    __syncthreads();
    if (t == 0) {
        float bs = 0.0f;
        #pragma unroll
        for (int w = 0; w < BLOCK / 64; ++w) bs += wsum[w];
        atomicAdd(acc, bs);
        __threadfence();
        const unsigned int done = atomicAdd(cnt, 1u);
        if (done == (unsigned int)(NB - 1)) {            // last block finalizes
            __threadfence();
            const float total = atomicAdd(acc, 0.0f);    // device-coherent read
            const double mean = 2.0 * (double)total / ((double)N * (double)N);
            out[(size_t)N * 3] = (float)(mean * 0.02);
        }
    }
}

extern "C" void kernel_launch(void* const* d_in, const int* in_sizes, int n_in,
                              void* d_out, int out_size, void* d_ws, size_t ws_size,
                              hipStream_t stream) {
    const float* pos = (const float*)d_in[0];
    float* out = (float*)d_out;
    float* acc = (float*)d_ws;
    unsigned int* cnt = (unsigned int*)d_ws + 1;

    hipMemsetAsync(d_ws, 0, 8, stream);   // acc = 0.f, cnt = 0

    pair_kernel<<<NB, BLOCK, 0, stream>>>(pos, out, acc, cnt);
}

// Round 4
// 122.412 us; speedup vs baseline: 1.0979x; 1.0979x over previous
//
#include <hip/hip_runtime.h>

// StericClashConstraint: N=16384 pts [N,3] fp32.
// out[0..3N-1] = pos passthrough; out[3N] = mean(max(1-dist,0), diag=0) * 0.02
//
// Round 4: upper-triangle symmetry (x2 at end) + single 512-pair vote per q
// (one branch per q, full ILP on the 24 independent fmas) + hw v_sqrt_f32.
// IPT=8 keeps the CU-shared LDS return pipe at ~0.73x of VALU-bound demand
// (1 broadcast ds_read_b128 per 512 pairs); IPT=4 would oversubscribe it 1.4x.
// Diag blocks fold j>i into the voted predicate (i==j never triggers the vote).

constexpr int N     = 16384;
constexpr int BLOCK = 128;            // 2 waves
constexpr int IPT   = 8;              // i's per thread
constexpr int IC    = BLOCK * IPT;    // 1024 i's per block
constexpr int NXC   = N / IC;         // 16 i-chunks
constexpr int SLAB  = 64;             // j's per block (staged once)
constexpr int SPC   = IC / SLAB;      // 16 j-slabs per chunk
constexpr int NDIAG = NXC * SPC;                    // 256
constexpr int NFULL = (NXC * (NXC - 1) / 2) * SPC;  // 1920
constexpr int NB    = NDIAG + NFULL;                // 2176 blocks, ~8.5/CU

__global__ void __launch_bounds__(BLOCK, 4)
pair_kernel(const float* __restrict__ pos, float* __restrict__ out,
            float* __restrict__ acc, unsigned int* __restrict__ cnt) {
    __shared__ float4 tile[SLAB];
    __shared__ float  wsum[BLOCK / 64];

    const int b = blockIdx.x;
    const int t = threadIdx.x;

    // ---- decode block -> (i-chunk x, j0, diag?) ; scalar/uniform
    int x, j0;
    bool diag;
    if (b < NDIAG) {
        x  = b / SPC;
        j0 = x * IC + (b % SPC) * SLAB;
        diag = true;
    } else {
        int b2 = b - NDIAG;
        x = 0;
        int c = (NXC - 1) * SPC;
        while (b2 >= c) { b2 -= c; ++x; c = (NXC - 1 - x) * SPC; }
        j0 = (x + 1) * IC + b2 * SLAB;
        diag = false;
    }

    // ---- pos -> out passthrough: 12288 float4 spread over 256 diag blocks
    if (diag && t < 48) {
        const int idx = b * 48 + t;
        reinterpret_cast<float4*>(out)[idx] =
            reinterpret_cast<const float4*>(pos)[idx];
    }

    // ---- stage j-tile {x,y,z,|p|^2}, once per block
    if (t < SLAB) {
        const float* p = pos + (size_t)(j0 + t) * 3;
        const float px = p[0], py = p[1], pz = p[2];
        tile[t] = make_float4(px, py, pz, fmaf(px, px, fmaf(py, py, pz * pz)));
    }

    // ---- i fragments (gram form): tt = sqj - 2*dot ; violation iff tt < thr = 1 - sqi
    const int ibt = x * IC + t;
    float xi2[IPT], yi2[IPT], zi2[IPT], thr[IPT], sqi[IPT];
    #pragma unroll
    for (int k = 0; k < IPT; ++k) {
        const float* p = pos + (size_t)(ibt + k * BLOCK) * 3;
        const float px = p[0], py = p[1], pz = p[2];
        xi2[k] = -2.0f * px;
        yi2[k] = -2.0f * py;
        zi2[k] = -2.0f * pz;
        sqi[k] = fmaf(px, px, fmaf(py, py, pz * pz));
        thr[k] = 1.0f - sqi[k];
    }

    __syncthreads();

    float s = 0.0f;
    if (!diag) {
        // full blocks: every pair here has j > i — no mask anywhere
        #pragma unroll 2
        for (int q = 0; q < SLAB; ++q) {
            const float4 pj = tile[q];
            float tt[IPT];
            unsigned long long m = 0;
            #pragma unroll
            for (int k = 0; k < IPT; ++k) {
                float d = fmaf(xi2[k], pj.x, pj.w);
                d = fmaf(yi2[k], pj.y, d);
                tt[k] = fmaf(zi2[k], pj.z, d);
                m |= __ballot(tt[k] < thr[k]);     // v_cmp -> sgpr pair + s_or (free)
            }
            if (m) {                                // one branch per 512 pairs, ~32% taken
                #pragma unroll
                for (int k = 0; k < IPT; ++k) {
                    if (tt[k] < thr[k]) {
                        const float d2 = fmaxf(tt[k] + sqi[k], 0.0f);
                        s += 1.0f - __builtin_amdgcn_sqrtf(d2);
                    }
                }
            }
        }
    } else {
        // diag blocks: j>i folded into the voted predicate (i==j never votes)
        #pragma unroll 2
        for (int q = 0; q < SLAB; ++q) {
            const float4 pj = tile[q];
            const int jq = j0 + q;
            float tt[IPT];
            unsigned long long m = 0;
            #pragma unroll
            for (int k = 0; k < IPT; ++k) {
                float d = fmaf(xi2[k], pj.x, pj.w);
                d = fmaf(yi2[k], pj.y, d);
                tt[k] = fmaf(zi2[k], pj.z, d);
                m |= __ballot((tt[k] < thr[k]) && (jq > ibt + k * BLOCK));
            }
            if (m) {
                #pragma unroll
                for (int k = 0; k < IPT; ++k) {
                    if ((tt[k] < thr[k]) && (jq > ibt + k * BLOCK)) {
                        const float d2 = fmaxf(tt[k] + sqi[k], 0.0f);
                        s += 1.0f - __builtin_amdgcn_sqrtf(d2);
                    }
                }
            }
        }
    }

    // ---- reduce: wave shuffle -> LDS -> one atomic per block
    for (int off = 32; off > 0; off >>= 1) s += __shfl_down(s, off);
    if ((t & 63) == 0) wsum[t >> 6] = s;
    __syncthreads();
    if (t == 0) {
        float bs = 0.0f;
        #pragma unroll
        for (int w = 0; w < BLOCK / 64; ++w) bs += wsum[w];
        atomicAdd(acc, bs);
        __threadfence();
        const unsigned int done = atomicAdd(cnt, 1u);
        if (done == (unsigned int)(NB - 1)) {        // last block finalizes
            __threadfence();
            const float total = atomicAdd(acc, 0.0f);  // device-coherent read
            const double mean = 2.0 * (double)total / ((double)N * (double)N);
            out[(size_t)N * 3] = (float)(mean * 0.02);
        }
    }
}

extern "C" void kernel_launch(void* const* d_in, const int* in_sizes, int n_in,
                              void* d_out, int out_size, void* d_ws, size_t ws_size,
                              hipStream_t stream) {
    const float* pos = (const float*)d_in[0];
    float* out = (float*)d_out;
    float* acc = (float*)d_ws;
    unsigned int* cnt = (unsigned int*)d_ws + 1;

    hipMemsetAsync(d_ws, 0, 8, stream);   // acc = 0.f, cnt = 0

    pair_kernel<<<NB, BLOCK, 0, stream>>>(pos, out, acc, cnt);
}

// Round 5
// 101.763 us; speedup vs baseline: 1.3207x; 1.2029x over previous
//
#include <hip/hip_runtime.h>

// StericClashConstraint: N=16384 pts [N,3] fp32.
// out[0..3N-1] = pos passthrough; out[3N] = mean(max(1-dist,0), diag=0) * 0.02
//
// Round 5: R4's lean loop (upper-triangle x2, gram form, one 512-pair vote/q,
// hw v_sqrt) was correct on VALU work (12.6us busy) but latency-bound
// (VALUBusy 18%). Fix: BLOCK=256 (4 waves, 4 blocks/CU resident) + q-batch=4
// register-pipelined ds_read_b128 prefetch so LDS latency is covered by
// in-flight loads instead of a dependent stall every q.

constexpr int N     = 16384;
constexpr int BLOCK = 256;            // 4 waves
constexpr int IPT   = 8;              // i's per thread
constexpr int IC    = BLOCK * IPT;    // 2048 i's per block
constexpr int NXC   = N / IC;         // 8 i-chunks
constexpr int SLAB  = 64;             // j's per block (staged once)
constexpr int SPC   = IC / SLAB;      // 32 j-slabs per chunk
constexpr int NDIAG = NXC * SPC;                    // 256
constexpr int NFULL = (NXC * (NXC - 1) / 2) * SPC;  // 896
constexpr int NB    = NDIAG + NFULL;                // 1152 blocks, 4.5/CU
constexpr int QB    = 4;              // tile entries prefetched per batch

__global__ void __launch_bounds__(BLOCK, 4)
pair_kernel(const float* __restrict__ pos, float* __restrict__ out,
            float* __restrict__ acc, unsigned int* __restrict__ cnt) {
    __shared__ float4 tile[SLAB];
    __shared__ float  wsum[BLOCK / 64];

    const int b = blockIdx.x;
    const int t = threadIdx.x;

    // ---- decode block -> (i-chunk x, j0, diag?) ; scalar/uniform
    int x, j0;
    bool diag;
    if (b < NDIAG) {
        x  = b / SPC;
        j0 = x * IC + (b % SPC) * SLAB;
        diag = true;
    } else {
        int b2 = b - NDIAG;
        x = 0;
        int c = (NXC - 1) * SPC;
        while (b2 >= c) { b2 -= c; ++x; c = (NXC - 1 - x) * SPC; }
        j0 = (x + 1) * IC + b2 * SLAB;
        diag = false;
    }

    // ---- pos -> out passthrough: 12288 float4 spread over 256 diag blocks
    if (diag && t < 48) {
        const int idx = b * 48 + t;
        reinterpret_cast<float4*>(out)[idx] =
            reinterpret_cast<const float4*>(pos)[idx];
    }

    // ---- stage j-tile {x,y,z,|p|^2}, once per block
    if (t < SLAB) {
        const float* p = pos + (size_t)(j0 + t) * 3;
        const float px = p[0], py = p[1], pz = p[2];
        tile[t] = make_float4(px, py, pz, fmaf(px, px, fmaf(py, py, pz * pz)));
    }

    // ---- i fragments (gram form): tt = sqj - 2*dot ; violation iff tt < thr = 1 - sqi
    const int ibt = x * IC + t;
    float xi2[IPT], yi2[IPT], zi2[IPT], thr[IPT], sqi[IPT];
    #pragma unroll
    for (int k = 0; k < IPT; ++k) {
        const float* p = pos + (size_t)(ibt + k * BLOCK) * 3;
        const float px = p[0], py = p[1], pz = p[2];
        xi2[k] = -2.0f * px;
        yi2[k] = -2.0f * py;
        zi2[k] = -2.0f * pz;
        sqi[k] = fmaf(px, px, fmaf(py, py, pz * pz));
        thr[k] = 1.0f - sqi[k];
    }

    __syncthreads();

    float s = 0.0f;
    if (!diag) {
        // full blocks: every pair has j > i — no mask
        float4 cur[QB];
        #pragma unroll
        for (int u = 0; u < QB; ++u) cur[u] = tile[u];
        for (int qb = 0; qb < SLAB; qb += QB) {
            float4 nxt[QB];
            const int nq = (qb + QB) & (SLAB - 1);   // wraps harmlessly on last iter
            #pragma unroll
            for (int u = 0; u < QB; ++u) nxt[u] = tile[nq + u];
            #pragma unroll
            for (int u = 0; u < QB; ++u) {
                const float4 pj = cur[u];
                float tt[IPT];
                unsigned long long m = 0;
                #pragma unroll
                for (int k = 0; k < IPT; ++k) {
                    float d = fmaf(xi2[k], pj.x, pj.w);
                    d = fmaf(yi2[k], pj.y, d);
                    tt[k] = fmaf(zi2[k], pj.z, d);
                    m |= __ballot(tt[k] < thr[k]);
                }
                if (m) {                               // ~32% taken per 512 pairs
                    #pragma unroll
                    for (int k = 0; k < IPT; ++k) {
                        if (tt[k] < thr[k]) {
                            const float d2 = fmaxf(tt[k] + sqi[k], 0.0f);
                            s += 1.0f - __builtin_amdgcn_sqrtf(d2);
                        }
                    }
                }
            }
            #pragma unroll
            for (int u = 0; u < QB; ++u) cur[u] = nxt[u];
        }
    } else {
        // diag blocks: j>i folded into the voted predicate (i==j never votes)
        float4 cur[QB];
        #pragma unroll
        for (int u = 0; u < QB; ++u) cur[u] = tile[u];
        for (int qb = 0; qb < SLAB; qb += QB) {
            float4 nxt[QB];
            const int nq = (qb + QB) & (SLAB - 1);
            #pragma unroll
            for (int u = 0; u < QB; ++u) nxt[u] = tile[nq + u];
            #pragma unroll
            for (int u = 0; u < QB; ++u) {
                const float4 pj = cur[u];
                const int jq = j0 + qb + u;
                float tt[IPT];
                unsigned long long m = 0;
                #pragma unroll
                for (int k = 0; k < IPT; ++k) {
                    float d = fmaf(xi2[k], pj.x, pj.w);
                    d = fmaf(yi2[k], pj.y, d);
                    tt[k] = fmaf(zi2[k], pj.z, d);
                    m |= __ballot((tt[k] < thr[k]) && (jq > ibt + k * BLOCK));
                }
                if (m) {
                    #pragma unroll
                    for (int k = 0; k < IPT; ++k) {
                        if ((tt[k] < thr[k]) && (jq > ibt + k * BLOCK)) {
                            const float d2 = fmaxf(tt[k] + sqi[k], 0.0f);
                            s += 1.0f - __builtin_amdgcn_sqrtf(d2);
                        }
                    }
                }
            }
            #pragma unroll
            for (int u = 0; u < QB; ++u) cur[u] = nxt[u];
        }
    }

    // ---- reduce: wave shuffle -> LDS -> one atomic per block
    for (int off = 32; off > 0; off >>= 1) s += __shfl_down(s, off);
    if ((t & 63) == 0) wsum[t >> 6] = s;
    __syncthreads();
    if (t == 0) {
        float bs = 0.0f;
        #pragma unroll
        for (int w = 0; w < BLOCK / 64; ++w) bs += wsum[w];
        atomicAdd(acc, bs);
        __threadfence();
        const unsigned int done = atomicAdd(cnt, 1u);
        if (done == (unsigned int)(NB - 1)) {          // last block finalizes
            __threadfence();
            const float total = atomicAdd(acc, 0.0f);  // device-coherent read
            const double mean = 2.0 * (double)total / ((double)N * (double)N);
            out[(size_t)N * 3] = (float)(mean * 0.02);
        }
    }
}

extern "C" void kernel_launch(void* const* d_in, const int* in_sizes, int n_in,
                              void* d_out, int out_size, void* d_ws, size_t ws_size,
                              hipStream_t stream) {
    const float* pos = (const float*)d_in[0];
    float* out = (float*)d_out;
    float* acc = (float*)d_ws;
    unsigned int* cnt = (unsigned int*)d_ws + 1;

    hipMemsetAsync(d_ws, 0, 8, stream);   // acc = 0.f, cnt = 0

    pair_kernel<<<NB, BLOCK, 0, stream>>>(pos, out, acc, cnt);
}

// Round 6
// 96.782 us; speedup vs baseline: 1.3887x; 1.0515x over previous
//
#include <hip/hip_runtime.h>

// StericClashConstraint: N=16384 pts [N,3] fp32.
// out[0..3N-1] = pos passthrough; out[3N] = mean(max(1-dist,0), diag=0) * 0.02
//
// Round 6: (a) no LDS in the hot loop — j-points are wave-uniform, so they are
// read from a repacked float4{x,y,z,sq} array at uniform addresses; compiler
// scalarizes these to s_load (K$-resident, SGPR operands feed v_fma directly).
// (b) perfectly balanced grid: 73728 upper-triangle j-columns / 1024 blocks =
// exactly 72 columns each; 1024 blocks = exactly 4/CU, all co-resident, no tail.
// (c) R4/R5 lean math kept: gram form, 8-ballot OR -> one branch per 512 pairs,
// hw v_sqrt. Diagonal excluded exactly by j>i inside the voted predicate.

constexpr int N     = 16384;
constexpr int BLOCK = 256;            // 4 waves
constexpr int IPT   = 8;              // i's per thread
constexpr int IC    = BLOCK * IPT;    // 2048 i's per chunk
constexpr int NXC   = N / IC;         // 8 i-chunks
constexpr int NB    = 1024;           // exactly 4 blocks/CU
constexpr int TCOLS = IC * (NXC * (NXC + 1) / 2);  // 73728 j-columns total
constexpr int CPB   = TCOLS / NB;     // 72 columns per block (exact)
constexpr int QB    = 4;              // j's prefetched per batch

__device__ __forceinline__ constexpr int cum(int x) {
    // columns before chunk x: sum_{x'<x} (NXC-x')*IC
    return IC * (x * NXC - x * (x - 1) / 2);
}

template <bool MASKED>
__device__ __forceinline__ float cols(const float4* __restrict__ jt4,
                                      int j0, int len, int ibt,
                                      const float (&xi2)[IPT], const float (&yi2)[IPT],
                                      const float (&zi2)[IPT], const float (&thr)[IPT],
                                      const float (&sqi)[IPT]) {
    float s = 0.0f;
    if (len <= 0) return s;
    float4 cur[QB];
    #pragma unroll
    for (int u = 0; u < QB; ++u) cur[u] = jt4[min(j0 + u, N - 1)];
    for (int qb = 0; qb < len; qb += QB) {
        float4 nxt[QB];
        #pragma unroll
        for (int u = 0; u < QB; ++u) nxt[u] = jt4[min(j0 + qb + QB + u, N - 1)];
        #pragma unroll
        for (int u = 0; u < QB; ++u) {
            const float4 pj = cur[u];
            const int jq = j0 + qb + u;
            float tt[IPT];
            unsigned long long m = 0;
            #pragma unroll
            for (int k = 0; k < IPT; ++k) {
                float d = fmaf(xi2[k], pj.x, pj.w);
                d = fmaf(yi2[k], pj.y, d);
                tt[k] = fmaf(zi2[k], pj.z, d);
                bool v = tt[k] < thr[k];
                if (MASKED) v = v && (jq > ibt + k * BLOCK);
                m |= __ballot(v);
            }
            if (m) {                      // one branch per 512 pairs
                #pragma unroll
                for (int k = 0; k < IPT; ++k) {
                    bool v = tt[k] < thr[k];
                    if (MASKED) v = v && (jq > ibt + k * BLOCK);
                    if (v) {
                        const float d2 = fmaxf(tt[k] + sqi[k], 0.0f);
                        s += 1.0f - __builtin_amdgcn_sqrtf(d2);
                    }
                }
            }
        }
        #pragma unroll
        for (int u = 0; u < QB; ++u) cur[u] = nxt[u];
    }
    return s;
}

__global__ void prep_kernel(const float* __restrict__ pos, float* __restrict__ out,
                            float4* __restrict__ jt4) {
    const int t = blockIdx.x * blockDim.x + threadIdx.x;   // 0..16383
    if (t < (N * 3) / 4) {
        reinterpret_cast<float4*>(out)[t] = reinterpret_cast<const float4*>(pos)[t];
    }
    const float x = pos[3 * t], y = pos[3 * t + 1], z = pos[3 * t + 2];
    jt4[t] = make_float4(x, y, z, fmaf(x, x, fmaf(y, y, z * z)));
}

__global__ void __launch_bounds__(BLOCK, 4)
pair_kernel(const float4* __restrict__ jt4, float* __restrict__ out,
            float* __restrict__ acc, unsigned int* __restrict__ cnt) {
    __shared__ float wsum[BLOCK / 64];
    const int b = blockIdx.x;
    const int t = threadIdx.x;

    float s = 0.0f;
    int c = b * CPB;
    const int c1 = c + CPB;

    while (c < c1) {                       // <=2 segments per block
        // uniform: chunk x containing column c
        int x = 0;
        #pragma unroll
        for (int xx = 1; xx < NXC; ++xx)
            if (cum(xx) <= c) x = xx;
        const int segEnd = min(c1, cum(x + 1));
        const int jbase  = x * IC + (c - cum(x));
        const int len    = segEnd - c;     // multiple of 4 by construction
        const int ibt    = x * IC + t;

        // i fragments from the repacked array (one dwordx4 per point)
        float xi2[IPT], yi2[IPT], zi2[IPT], thr[IPT], sqi[IPT];
        #pragma unroll
        for (int k = 0; k < IPT; ++k) {
            const float4 w = jt4[ibt + k * BLOCK];
            xi2[k] = -2.0f * w.x;
            yi2[k] = -2.0f * w.y;
            zi2[k] = -2.0f * w.z;
            sqi[k] = w.w;
            thr[k] = 1.0f - w.w;
        }

        // masked part: columns whose j lies inside this i-chunk (needs j>i)
        const int maskLen = min(len, max(0, (x + 1) * IC - jbase));
        s += cols<true >(jt4, jbase, maskLen, ibt, xi2, yi2, zi2, thr, sqi);
        s += cols<false>(jt4, jbase + maskLen, len - maskLen, ibt, xi2, yi2, zi2, thr, sqi);
        c = segEnd;
    }

    // reduce: wave shuffle -> LDS -> one atomic per block
    for (int off = 32; off > 0; off >>= 1) s += __shfl_down(s, off);
    if ((t & 63) == 0) wsum[t >> 6] = s;
    __syncthreads();
    if (t == 0) {
        float bs = 0.0f;
        #pragma unroll
        for (int w = 0; w < BLOCK / 64; ++w) bs += wsum[w];
        atomicAdd(acc, bs);
        __threadfence();
        const unsigned int done = atomicAdd(cnt, 1u);
        if (done == (unsigned int)(NB - 1)) {          // last block finalizes
            __threadfence();
            const float total = atomicAdd(acc, 0.0f);  // device-coherent read
            const double mean = 2.0 * (double)total / ((double)N * (double)N);
            out[(size_t)N * 3] = (float)(mean * 0.02);
        }
    }
}

extern "C" void kernel_launch(void* const* d_in, const int* in_sizes, int n_in,
                              void* d_out, int out_size, void* d_ws, size_t ws_size,
                              hipStream_t stream) {
    const float* pos = (const float*)d_in[0];
    float* out = (float*)d_out;
    // ws layout: [acc(4B) cnt(4B) pad..256B) | jt4: 16384 x float4 (256 KiB)]
    float* acc = (float*)d_ws;
    unsigned int* cnt = (unsigned int*)d_ws + 1;
    float4* jt4 = (float4*)((char*)d_ws + 256);

    hipMemsetAsync(d_ws, 0, 8, stream);   // acc = 0.f, cnt = 0

    prep_kernel<<<N / 256, 256, 0, stream>>>(pos, out, jt4);
    pair_kernel<<<NB, BLOCK, 0, stream>>>(jt4, out, acc, cnt);
}